// Round 12
// baseline (208.717 us; speedup 1.0000x reference)
//
#include <hip/hip_runtime.h>

#define IMG 224
#define PATCHSZ 16
#define CHN 3
#define DDIM 768
#define ROWN 14
#define NPATCH 196
#define PDIM 768
#define BATCH 32

#define DTILE 128                 // d-cols per block (6 blocks per patch)
#define NDBLK (DDIM / DTILE)      // 6
#define KCHUNK 64                 // P chunk rows
#define NCHUNK (PDIM / KCHUNK)    // 12
#define KSUB 16                   // W subchunk rows
#define NSUB (PDIM / KSUB)        // 48
#define NWG (NPATCH * NDBLK)      // 1176 = 8 * 147

// Kernel 1: x[32][3][224][224] -> P[196][32][768]
__global__ void extract_patches_kernel(const float* __restrict__ x,
                                       float* __restrict__ P) {
    int i = blockIdx.x * blockDim.x + threadIdx.x;
    if (i >= NPATCH * BATCH * PDIM) return;
    int k  = i % PDIM;
    int nb = i / PDIM;
    int b  = nb % BATCH;
    int n  = nb / BATCH;
    int ch = k >> 8;
    int py = (k >> 4) & 15;
    int px = k & 15;
    int r = n / ROWN, c = n % ROWN;
    P[i] = x[(((size_t)b * CHN + ch) * IMG + r * PATCHSZ + py) * IMG
             + c * PATCHSZ + px];
}

// packed fp32 FMA, P-value broadcast via op_sel (no mov):
#define PK_FMA_LO(a2, w2, p2)                                                \
    asm("v_pk_fma_f32 %0, %1, %2, %0 op_sel:[0,0,0] op_sel_hi:[1,0,1]"       \
        : "+v"(a2) : "v"(w2), "v"(p2))
#define PK_FMA_HI(a2, w2, p2)                                                \
    asm("v_pk_fma_f32 %0, %1, %2, %0 op_sel:[0,1,0] op_sel_hi:[1,1,1]"       \
        : "+v"(a2) : "v"(w2), "v"(p2))

// per patch n: out[:,n,d0:d0+128] = P[n] (32x768) * W[n][:,d0:d0+128] + bias
// grid 1176 (all-resident, 5 blocks/CU), block 128 (2 waves);
// thread tile 8 batches x 4 d-cols. W: global_load_lds double-buffer.
// XCD-chunked swizzle keeps a patch's 6 blocks on one XCD (P L2 reuse).
__global__ __launch_bounds__(128, 2) void patch_gemm_kernel(
    const float* __restrict__ P,    // [196][32][768]
    const float* __restrict__ W,    // [196][768][768]
    const float* __restrict__ bias, // [196][768]
    float* __restrict__ out)        // [32][196][768]
{
    __shared__ __align__(16) float wt[2][KSUB][DTILE];   // 16 KB W ping-pong
    __shared__ __align__(16) float ap[2][KCHUNK][BATCH]; // 16 KB P ping-pong

    // bijective XCD-chunk swizzle: 1176 = 8 * 147 exactly
    const int wid  = (blockIdx.x & 7) * (NWG / 8) + (blockIdx.x >> 3);
    const int n    = wid / NDBLK;
    const int dblk = wid % NDBLK;
    const int t    = threadIdx.x;   // 0..127
    const int l    = t & 63;        // lane
    const int wv   = t >> 6;        // wave 0..1
    const int dq   = t & 31;        // d-quad 0..31
    const int b0   = (t >> 5) * 8;  // batch group 0..3 -> 8 batches
    const int d    = dblk * DTILE + dq * 4;

    const float* Wn0 = W + (size_t)n * PDIM * DDIM + dblk * DTILE;
    const float* Pn  = P + (size_t)n * BATCH * PDIM;

    // P staging mapping: thread -> (batch sb, 16 consecutive k at sk)
    const int sb = t >> 2;            // 0..31
    const int sk = (t & 3) * 16;      // 0,16,32,48

    float2 acc[8][2];
#pragma unroll
    for (int i = 0; i < 8; ++i) {
        acc[i][0] = make_float2(0.f, 0.f);
        acc[i][1] = make_float2(0.f, 0.f);
    }

    // issue one W subchunk (16 rows x 128 cols, 8 KB) into wt[u&1].
    // lane-linear dest: dest_off = j*2KB + wv*1KB + l*16B
    //   -> row = j*4 + wv*2 + (l>>5), col = (l&31)*4   (512B per 32 lanes)
    auto issueW = [&](int u) {
        const float* src = Wn0 + (size_t)u * KSUB * DDIM;
        float* dst = &wt[u & 1][0][0];
#pragma unroll
        for (int j = 0; j < 4; ++j) {
            const int row = j * 4 + wv * 2 + (l >> 5);
            const int col = (l & 31) * 4;
            __builtin_amdgcn_global_load_lds(
                (const __attribute__((address_space(1))) unsigned int*)
                    (src + (size_t)row * DDIM + col),
                (__attribute__((address_space(3))) unsigned int*)
                    (dst + row * DTILE + col),
                16, 0, 0);
        }
    };

    // prologue: stage P chunk 0, prefetch P chunk 1, issue W subchunk 0
    {
        const float* s = Pn + (size_t)sb * PDIM + sk;
        float (*apb)[BATCH] = ap[0];
#pragma unroll
        for (int j = 0; j < 4; ++j) {
            float4 v = *reinterpret_cast<const float4*>(s + j * 4);
            apb[sk + j * 4 + 0][sb] = v.x;
            apb[sk + j * 4 + 1][sb] = v.y;
            apb[sk + j * 4 + 2][sb] = v.z;
            apb[sk + j * 4 + 3][sb] = v.w;
        }
    }
    float4 pn[4];
    {
        const float* s = Pn + (size_t)sb * PDIM + KCHUNK + sk;
#pragma unroll
        for (int j = 0; j < 4; ++j)
            pn[j] = *reinterpret_cast<const float4*>(s + j * 4);
    }
    issueW(0);

#pragma unroll 1
    for (int u = 0; u < NSUB; ++u) {
        __syncthreads();   // drains vmcnt+lgkmcnt: W(u) landed, P visible
        if (u + 1 < NSUB) issueW(u + 1);

        const int c  = u >> 2;          // P chunk index
        const int kb = (u & 3) * KSUB;  // k offset within P chunk
        const float* wbuf = &wt[u & 1][0][0] + dq * 4;
        const float* pbuf = &ap[c & 1][0][0] + b0;

#pragma unroll 4
        for (int kk = 0; kk < KSUB; ++kk) {
            const float* wp = wbuf + kk * DTILE;
            float2 wlo = *reinterpret_cast<const float2*>(wp);
            float2 whi = *reinterpret_cast<const float2*>(wp + 2);
            const float* pp = pbuf + (size_t)(kb + kk) * BATCH;
            // broadcast LDS reads (wave-uniform per 32-lane group)
            float2 p01 = *reinterpret_cast<const float2*>(pp);
            float2 p23 = *reinterpret_cast<const float2*>(pp + 2);
            float2 p45 = *reinterpret_cast<const float2*>(pp + 4);
            float2 p67 = *reinterpret_cast<const float2*>(pp + 6);

            PK_FMA_LO(acc[0][0], wlo, p01); PK_FMA_LO(acc[0][1], whi, p01);
            PK_FMA_HI(acc[1][0], wlo, p01); PK_FMA_HI(acc[1][1], whi, p01);
            PK_FMA_LO(acc[2][0], wlo, p23); PK_FMA_LO(acc[2][1], whi, p23);
            PK_FMA_HI(acc[3][0], wlo, p23); PK_FMA_HI(acc[3][1], whi, p23);
            PK_FMA_LO(acc[4][0], wlo, p45); PK_FMA_LO(acc[4][1], whi, p45);
            PK_FMA_HI(acc[5][0], wlo, p45); PK_FMA_HI(acc[5][1], whi, p45);
            PK_FMA_LO(acc[6][0], wlo, p67); PK_FMA_LO(acc[6][1], whi, p67);
            PK_FMA_HI(acc[7][0], wlo, p67); PK_FMA_HI(acc[7][1], whi, p67);
        }

        // at the last subchunk of chunk c: stage P chunk c+1, prefetch c+2
        if ((u & 3) == 3 && c + 1 < NCHUNK) {
            float (*apb)[BATCH] = ap[(c + 1) & 1];
#pragma unroll
            for (int j = 0; j < 4; ++j) {
                apb[sk + j * 4 + 0][sb] = pn[j].x;
                apb[sk + j * 4 + 1][sb] = pn[j].y;
                apb[sk + j * 4 + 2][sb] = pn[j].z;
                apb[sk + j * 4 + 3][sb] = pn[j].w;
            }
            if (c + 2 < NCHUNK) {
                const float* s = Pn + (size_t)sb * PDIM + (c + 2) * KCHUNK + sk;
#pragma unroll
                for (int j = 0; j < 4; ++j)
                    pn[j] = *reinterpret_cast<const float4*>(s + j * 4);
            }
        }
    }

    float4 bv = *reinterpret_cast<const float4*>(bias + (size_t)n * DDIM + d);
#pragma unroll
    for (int i = 0; i < 8; ++i) {
        const int b = b0 + i;
        float4 o;
        o.x = acc[i][0].x + bv.x;
        o.y = acc[i][0].y + bv.y;
        o.z = acc[i][1].x + bv.z;
        o.w = acc[i][1].y + bv.w;
        *reinterpret_cast<float4*>(out + ((size_t)b * NPATCH + n) * DDIM + d) = o;
    }
}

extern "C" void kernel_launch(void* const* d_in, const int* in_sizes, int n_in,
                              void* d_out, int out_size, void* d_ws, size_t ws_size,
                              hipStream_t stream) {
    const float* x    = (const float*)d_in[0];
    const float* W    = (const float*)d_in[1];
    const float* bias = (const float*)d_in[2];
    float* out = (float*)d_out;
    float* P   = (float*)d_ws;   // 196*32*768*4 = 19.3 MB

    int total = NPATCH * BATCH * PDIM;
    extract_patches_kernel<<<(total + 255) / 256, 256, 0, stream>>>(x, P);
    patch_gemm_kernel<<<NWG, 128, 0, stream>>>(P, W, bias, out);
}

// Round 13
// 168.070 us; speedup vs baseline: 1.2418x; 1.2418x over previous
//
#include <hip/hip_runtime.h>

#define IMG 224
#define PATCHSZ 16
#define CHN 3
#define DDIM 768
#define ROWN 14
#define NPATCH 196
#define PDIM 768
#define BATCH 32

#define DTILE 256                 // d-cols per block (3 blocks per patch)
#define NDBLK (DDIM / DTILE)      // 3
#define KCHUNK 64                 // P chunk rows
#define NCHUNK (PDIM / KCHUNK)    // 12
#define KSUB 16                   // W subchunk rows
#define NSUB (PDIM / KSUB)        // 48

// Kernel 1: x[32][3][224][224] -> P[196][32][768]
__global__ void extract_patches_kernel(const float* __restrict__ x,
                                       float* __restrict__ P) {
    int i = blockIdx.x * blockDim.x + threadIdx.x;
    if (i >= NPATCH * BATCH * PDIM) return;
    int k  = i % PDIM;
    int nb = i / PDIM;
    int b  = nb % BATCH;
    int n  = nb / BATCH;
    int ch = k >> 8;
    int py = (k >> 4) & 15;
    int px = k & 15;
    int r = n / ROWN, c = n % ROWN;
    P[i] = x[(((size_t)b * CHN + ch) * IMG + r * PATCHSZ + py) * IMG
             + c * PATCHSZ + px];
}

#define ACC_ROW(i, pv, wj)                                                   \
    acc[i][0] = fmaf(pv, wj.x, acc[i][0]);                                   \
    acc[i][1] = fmaf(pv, wj.y, acc[i][1]);                                   \
    acc[i][2] = fmaf(pv, wj.z, acc[i][2]);                                   \
    acc[i][3] = fmaf(pv, wj.w, acc[i][3]);

// per patch n: out[:,n,d0:d0+256] = P[n] (32x768) * W[n][:,d0:d0+256] + bias
// grid 196*3, block 256; thread tile 8 batches x 4 d-cols.
// NEW lane map: wave wv owns d-slice [wv*64, wv*64+64); lane = (bg<<4)|dq16.
//   -> W LDS read per wave touches only 256 distinct bytes (16 lanes),
//      other lanes are same-address broadcasts (free) — kills the 4x
//      cross-wave W duplication of the r4 mapping.
// W: global_load_lds double-buffer (unchanged from r4).
__global__ __launch_bounds__(256, 2) void patch_gemm_kernel(
    const float* __restrict__ P,    // [196][32][768]
    const float* __restrict__ W,    // [196][768][768]
    const float* __restrict__ bias, // [196][768]
    float* __restrict__ out)        // [32][196][768]
{
    __shared__ __align__(16) float wt[2][KSUB][DTILE];   // 32 KB W ping-pong
    __shared__ __align__(16) float ap[2][KCHUNK][BATCH]; // 16 KB P ping-pong

    const int blk  = blockIdx.x;
    const int n    = blk / NDBLK;
    const int dblk = blk % NDBLK;
    const int tid  = threadIdx.x;
    const int ln   = tid & 63;      // lane
    const int wv   = tid >> 6;      // wave 0..3
    const int dq   = ln & 15;       // d-quad within wave's 64-col slice
    const int b0   = (ln >> 4) * 8; // batch group 0..3 -> 8 batches
    const int dofs = wv * 64 + dq * 4;          // col within the 256 tile
    const int d    = dblk * DTILE + dofs;

    const float* Wn0 = W + (size_t)n * PDIM * DDIM + dblk * DTILE;
    const float* Pn  = P + (size_t)n * BATCH * PDIM;

    // P staging mapping (verbatim r4): thread -> (batch sb, 8 k at sk)
    const int sb = tid >> 3;          // 0..31
    const int sk = (tid & 7) * 8;     // 0..56

    float acc[8][4];
#pragma unroll
    for (int i = 0; i < 8; ++i)
#pragma unroll
        for (int j = 0; j < 4; ++j) acc[i][j] = 0.f;

    // issue one W subchunk (16 rows x 256 cols, 16 KB) into wt[u&1].
    // per wave: 4 x global_load_lds_dwordx4, one 1KB row each (verbatim r4).
    auto issueW = [&](int u) {
        const float* src = Wn0 + (size_t)u * KSUB * DDIM;
        float* dst = &wt[u & 1][0][0];
#pragma unroll
        for (int j = 0; j < 4; ++j) {
            const int row = wv * 4 + j;
            __builtin_amdgcn_global_load_lds(
                (const __attribute__((address_space(1))) unsigned int*)
                    (src + (size_t)row * DDIM + ln * 4),
                (__attribute__((address_space(3))) unsigned int*)
                    (dst + row * DTILE + ln * 4),
                16, 0, 0);
        }
    };

    // prologue: stage P chunk 0, prefetch P chunk 1, issue W subchunk 0
    {
        const float* s = Pn + (size_t)sb * PDIM + sk;
        float4 v0 = *reinterpret_cast<const float4*>(s);
        float4 v1 = *reinterpret_cast<const float4*>(s + 4);
        float (*apb)[BATCH] = ap[0];
        apb[sk + 0][sb] = v0.x; apb[sk + 1][sb] = v0.y;
        apb[sk + 2][sb] = v0.z; apb[sk + 3][sb] = v0.w;
        apb[sk + 4][sb] = v1.x; apb[sk + 5][sb] = v1.y;
        apb[sk + 6][sb] = v1.z; apb[sk + 7][sb] = v1.w;
    }
    float4 pn0, pn1;
    {
        const float* s = Pn + (size_t)sb * PDIM + KCHUNK + sk;
        pn0 = *reinterpret_cast<const float4*>(s);
        pn1 = *reinterpret_cast<const float4*>(s + 4);
    }
    issueW(0);

#pragma unroll 1
    for (int u = 0; u < NSUB; ++u) {
        __syncthreads();   // drains vmcnt+lgkmcnt: W(u) landed, P visible
        if (u + 1 < NSUB) issueW(u + 1);

        const int c  = u >> 2;          // P chunk index
        const int kb = (u & 3) * KSUB;  // k offset within P chunk
        const float* wbuf = &wt[u & 1][0][0] + dofs;
        const float* pbuf = &ap[c & 1][0][0] + b0;

#pragma unroll 4
        for (int kk = 0; kk < KSUB; ++kk) {
            float4 w = *reinterpret_cast<const float4*>(wbuf + kk * DTILE);
            const float* pp = pbuf + (size_t)(kb + kk) * BATCH;
            // 4 distinct 32B segments per wave, disjoint banks
            float4 p01 = *reinterpret_cast<const float4*>(pp);
            float4 p23 = *reinterpret_cast<const float4*>(pp + 4);
            ACC_ROW(0, p01.x, w) ACC_ROW(1, p01.y, w)
            ACC_ROW(2, p01.z, w) ACC_ROW(3, p01.w, w)
            ACC_ROW(4, p23.x, w) ACC_ROW(5, p23.y, w)
            ACC_ROW(6, p23.z, w) ACC_ROW(7, p23.w, w)
        }

        // at the last subchunk of chunk c: stage P chunk c+1, prefetch c+2
        if ((u & 3) == 3 && c + 1 < NCHUNK) {
            float (*apb)[BATCH] = ap[(c + 1) & 1];
            apb[sk + 0][sb] = pn0.x; apb[sk + 1][sb] = pn0.y;
            apb[sk + 2][sb] = pn0.z; apb[sk + 3][sb] = pn0.w;
            apb[sk + 4][sb] = pn1.x; apb[sk + 5][sb] = pn1.y;
            apb[sk + 6][sb] = pn1.z; apb[sk + 7][sb] = pn1.w;
            if (c + 2 < NCHUNK) {
                const float* s = Pn + (size_t)sb * PDIM + (c + 2) * KCHUNK + sk;
                pn0 = *reinterpret_cast<const float4*>(s);
                pn1 = *reinterpret_cast<const float4*>(s + 4);
            }
        }
    }

    float4 bv = *reinterpret_cast<const float4*>(bias + (size_t)n * DDIM + d);
#pragma unroll
    for (int i = 0; i < 8; ++i) {
        const int b = b0 + i;
        float4 o;
        o.x = acc[i][0] + bv.x;
        o.y = acc[i][1] + bv.y;
        o.z = acc[i][2] + bv.z;
        o.w = acc[i][3] + bv.w;
        *reinterpret_cast<float4*>(out + ((size_t)b * NPATCH + n) * DDIM + d) = o;
    }
}

extern "C" void kernel_launch(void* const* d_in, const int* in_sizes, int n_in,
                              void* d_out, int out_size, void* d_ws, size_t ws_size,
                              hipStream_t stream) {
    const float* x    = (const float*)d_in[0];
    const float* W    = (const float*)d_in[1];
    const float* bias = (const float*)d_in[2];
    float* out = (float*)d_out;
    float* P   = (float*)d_ws;   // 196*32*768*4 = 19.3 MB

    int total = NPATCH * BATCH * PDIM;
    extract_patches_kernel<<<(total + 255) / 256, 256, 0, stream>>>(x, P);
    patch_gemm_kernel<<<NPATCH * NDBLK, 256, 0, stream>>>(P, W, bias, out);
}